// Round 13
// baseline (207.131 us; speedup 1.0000x reference)
//
#include <hip/hip_runtime.h>
#include <hip/hip_bf16.h>

// FraudGNN: 2-layer GraphSAGE (mean aggr) + linear head.
// N=100000, E=1600000, feat 48 -> 32 -> 16 -> 2. fp32 in/out, int edge_index.
//
// R13 = R9 (x4 padding, unroll-4 gathers, fp32-LDS lin2 weights -- all the
// proven optima) + degree-binned node permutation:
//  Gather waves hold 16 (g1) / 32 (g2) nodes; loop trip = MAX degree in the
//  wave (Poisson(16): E[max16] ~ 26 vs mean 16 -> ~40% dead lanes). k2 now
//  counting-sorts its 256 nodes by degree into perm[]; gathers process nodes
//  in perm order -> waves see uniform degrees, divergence ~ 0.
//
//  K1 = lin2 || bucket1 (block-ranged fusion, in-block int64 detect)
//  K2 = per-bucket CSR fill (fixed b*SEG region, x4-padded) + local deg-sort
//  K3 = gather1: 4 lanes/node via perm, unroll-4, fused update + layer-2 proj
//  K4 = gather2: 2 lanes/node via perm, unroll-4, fused final head
// Algebra: mean(x[src])@Wl == segsum((x@Wl)[src])/cnt -> project first,
// aggregate 32/16-wide bf16 rows by gather (zero float atomics).

constexpr int NN  = 100000;
constexpr int NE  = 1600000;
constexpr int NCH = (NN + 255) / 256;   // 391 node chunks (lin2 blocks)
constexpr int NB  = 391;                // buckets = dst >> 8
constexpr int CAP = 4608;               // per-bucket capacity (mean 4092, +8 sigma)
constexpr int SEG = CAP + 3 * 256;      // 5376: worst-case x4-padded footprint
constexpr int T1  = 2048;               // edges per bucket1 block
constexpr int EPT = T1 / 256;           // 8 edges cached per thread
constexpr int NB1 = (NE + T1 - 1) / T1; // 782 bucket1 blocks
constexpr int NSLOT = NB * 256;         // 100096 perm slots

__device__ __forceinline__ float bl(unsigned u) { return __uint_as_float(u << 16); }
__device__ __forceinline__ float bh(unsigned u) { return __uint_as_float(u & 0xffff0000u); }
__device__ __forceinline__ unsigned f2b(float x) {
    unsigned u = __float_as_uint(x);
    return (u + 0x7fffu + ((u >> 16) & 1u)) >> 16;
}
__device__ __forceinline__ unsigned pack2(float a, float b) {
    return f2b(a) | (f2b(b) << 16);
}

__device__ __forceinline__ int wave_incl_scan(int v, int lane) {
#pragma unroll
    for (int d = 1; d < 64; d <<= 1) {
        int t = __shfl_up(v, d, 64);
        if (lane >= d) v += t;
    }
    return v;
}

// ---- K1: lin2 (blocks [0,NCH)) || bucket1 (blocks [NCH, NCH+NB1)) ----------
__global__ __launch_bounds__(256) void k1_kernel(
    const float* __restrict__ X,
    const float* __restrict__ Wl,
    const float* __restrict__ Wr,
    const int*   __restrict__ ei,
    int* __restrict__ bsize, unsigned* __restrict__ bbuf,
    __hip_bfloat16* __restrict__ P, __hip_bfloat16* __restrict__ R)
{
    __shared__ float sW[2][48 * 32];            // 12 KB (lin part, fp32: R9 optimum)
    __shared__ int hist[NB], base[NB], cur[NB]; // 4.7 KB (bucket part)
    __shared__ int s_any;

    if (blockIdx.x < NCH) {
        // ------ lin2: P = X@Wl, R = X@Wr (+ zero row at NN) ------
        for (int i = threadIdx.x; i < 48 * 32; i += 256) {
            sW[0][i] = Wl[i];
            sW[1][i] = Wr[i];
        }
        __syncthreads();
        int n = blockIdx.x * 256 + threadIdx.x;
        if (n > NN) return;
        if (n == NN) {                           // zero row (CSR pad target)
            uint4 z = make_uint4(0, 0, 0, 0);
            uint4* pp = reinterpret_cast<uint4*>(P + (size_t)NN * 32);
#pragma unroll
            for (int i = 0; i < 4; ++i) pp[i] = z;
            return;
        }
        float xr[48];
        const float4* xp = reinterpret_cast<const float4*>(X + (size_t)n * 48);
#pragma unroll
        for (int i = 0; i < 12; ++i) {
            float4 u = xp[i];
            xr[i*4+0] = u.x; xr[i*4+1] = u.y; xr[i*4+2] = u.z; xr[i*4+3] = u.w;
        }
        float accp[32], accr[32];
#pragma unroll
        for (int j = 0; j < 32; ++j) { accp[j] = 0.f; accr[j] = 0.f; }
#pragma unroll
        for (int k = 0; k < 48; ++k) {
            float xk = xr[k];
#pragma unroll
            for (int j = 0; j < 32; ++j) {
                accp[j] += xk * sW[0][k * 32 + j];
                accr[j] += xk * sW[1][k * 32 + j];
            }
        }
        uint4* pp = reinterpret_cast<uint4*>(P + (size_t)n * 32);
        uint4* rp = reinterpret_cast<uint4*>(R + (size_t)n * 32);
#pragma unroll
        for (int i = 0; i < 4; ++i) {
            uint4 u, v;
            u.x = pack2(accp[i*8+0], accp[i*8+1]); u.y = pack2(accp[i*8+2], accp[i*8+3]);
            u.z = pack2(accp[i*8+4], accp[i*8+5]); u.w = pack2(accp[i*8+6], accp[i*8+7]);
            v.x = pack2(accr[i*8+0], accr[i*8+1]); v.y = pack2(accr[i*8+2], accr[i*8+3]);
            v.z = pack2(accr[i*8+4], accr[i*8+5]); v.w = pack2(accr[i*8+6], accr[i*8+7]);
            pp[i] = u;
            rp[i] = v;
        }
    } else {
        // ------ bucket1: coarse sort edges by dst>>8 ------
        if (threadIdx.x == 0) s_any = 0;
        for (int i = threadIdx.x; i < NB; i += 256) { hist[i] = 0; cur[i] = 0; }
        __syncthreads();
        // self-detect edge_index layout: int64 -> odd words all zero
        int dv = 0;
        for (int i = threadIdx.x; i < 2048; i += 256) dv |= ei[2 * i + 1];
        if (dv != 0) atomicOr(&s_any, 1);
        __syncthreads();
        int sh = (s_any == 0) ? 1 : 0;

        int e0 = (blockIdx.x - NCH) * T1;
        int sreg[EPT], dreg[EPT];
#pragma unroll
        for (int it = 0; it < EPT; ++it) {
            int e = e0 + it * 256 + threadIdx.x;
            bool ok = e < NE;
            int s = ok ? ei[(size_t)e << sh] : -1;
            int d = ok ? ei[(size_t)(NE + e) << sh] : -1;
            if ((unsigned)s >= (unsigned)NN || (unsigned)d >= (unsigned)NN) { s = -1; d = -1; }
            sreg[it] = s; dreg[it] = d;
            if (d >= 0) atomicAdd(&hist[d >> 8], 1);
        }
        __syncthreads();
        for (int b = threadIdx.x; b < NB; b += 256) {
            int h = hist[b];
            base[b] = h ? atomicAdd(&bsize[b], h) : 0;
        }
        __syncthreads();
#pragma unroll
        for (int it = 0; it < EPT; ++it) {
            int s = sreg[it], d = dreg[it];
            if (d < 0) continue;
            int b = d >> 8;
            int pos = base[b] + atomicAdd(&cur[b], 1);
            if (pos < CAP)
                bbuf[(size_t)b * CAP + pos] = ((unsigned)s << 8) | (unsigned)(d & 255);
        }
    }
}

// ---- K2: per-bucket CSR fill (x4-padded) + local degree-sorted perm ---------
__global__ __launch_bounds__(256) void k2_kernel(
    const int* __restrict__ bsize, const unsigned* __restrict__ bbuf,
    int* __restrict__ deg, int* __restrict__ rowstart, int* __restrict__ csr_src,
    int* __restrict__ perm)
{
    __shared__ int ldeg[256], lcur[256], ws[4], phist[64];
    int b = blockIdx.x, t = threadIdx.x;
    int bs = b * SEG;                       // fixed region: no cross-bucket coupling

    int S = min(bsize[b], CAP);
    const unsigned* bp = bbuf + (size_t)b * CAP;
    ldeg[t] = 0;
    if (t < 64) phist[t] = 0;
    __syncthreads();
    for (int i = t; i < S; i += 256)
        atomicAdd(&ldeg[bp[i] & 255u], 1);
    __syncthreads();

    int v  = ldeg[t];
    int pv = (v + 3) & ~3;                  // x4-padded per-node length
    int lane = t & 63, wid = t >> 6;
    int incl = wave_incl_scan(pv, lane);
    if (lane == 63) ws[wid] = incl;
    __syncthreads();
    int off = 0;
#pragma unroll
    for (int w = 0; w < 3; ++w)
        if (wid > w) off += ws[w];
    int excl = off + incl - pv;             // <= SEG - pv

    int node = (b << 8) + t;
    bool validn = node < NN;
    if (validn) {
        deg[node] = v;
        rowstart[node] = bs + excl;         // 4-aligned
    }
    lcur[t] = excl;

    // --- local degree counting sort -> perm (divergence-free gather waves) ---
    int bin = min(v, 63);
    if (validn) atomicAdd(&phist[bin], 1);
    __syncthreads();
    if (t < 64) {
        int c = phist[t];
        int ip = wave_incl_scan(c, t);
        phist[t] = ip - c;                  // exclusive start; doubles as cursor
    }
    __syncthreads();
    if (validn) {
        int pos = atomicAdd(&phist[bin], 1);
        perm[(b << 8) + pos] = node;        // pos in [0, valid)
    } else {
        perm[(b << 8) + t] = node;          // t >= valid -> disjoint slots
    }

    // --- CSR fill + pads (unchanged) ---
    for (int i = t; i < S; i += 256) {
        unsigned pk = bp[i];
        int pos = atomicAdd(&lcur[pk & 255u], 1);
        csr_src[bs + pos] = (int)(pk >> 8);
    }
    for (int p = excl + v; p < excl + pv; ++p)  // pad with zero-row id
        csr_src[bs + p] = NN;
}

// ---- K3: layer1 gather (perm order, unroll-4) + update + layer-2 proj -------
__global__ __launch_bounds__(256) void gather1f_kernel(
    const int* __restrict__ perm,
    const int* __restrict__ rowstart, const int* __restrict__ deg,
    const int* __restrict__ csr_src,
    const __hip_bfloat16* __restrict__ p1,     // [N+1,32] (row NN = 0)
    const __hip_bfloat16* __restrict__ r1,     // [N,32]
    const float* __restrict__ b1,              // [32]
    const float* __restrict__ W2l,             // [32,16]
    const float* __restrict__ W2r,             // [32,16]
    __hip_bfloat16* __restrict__ P2,           // [N+1,16] (row NN = 0)
    __hip_bfloat16* __restrict__ R2)           // [N+1,16]
{
    __shared__ float sW2l[32 * 16], sW2r[32 * 16], sb1[32];
    __shared__ float shh[32 * 64];             // h exchange, 8 KB
    int t = threadIdx.x;
    for (int i = t; i < 32 * 16; i += 256) { sW2l[i] = W2l[i]; sW2r[i] = W2r[i]; }
    if (t < 32) sb1[t] = b1[t];
    __syncthreads();

    int loc = t >> 2, c = t & 3;
    int slot = blockIdx.x * 64 + loc;          // < NSLOT by grid sizing
    int n = perm[slot];
    bool valid = n < NN;

    if (valid) {
        int start = rowstart[n], dn = deg[n];
        int pv4 = ((dn + 3) & ~3) >> 2;
        float acc[8];
#pragma unroll
        for (int j = 0; j < 8; ++j) acc[j] = 0.f;
        const uint4* prow = reinterpret_cast<const uint4*>(p1);
        const int4* cp4 = reinterpret_cast<const int4*>(csr_src + start);
        for (int k = 0; k < pv4; ++k) {         // 4 row fetches in flight
            int4 s4 = cp4[k];
            uint4 a = prow[(size_t)s4.x * 4 + c];
            uint4 b = prow[(size_t)s4.y * 4 + c];
            uint4 d = prow[(size_t)s4.z * 4 + c];
            uint4 e = prow[(size_t)s4.w * 4 + c];
            acc[0] += bl(a.x) + bl(b.x) + bl(d.x) + bl(e.x);
            acc[1] += bh(a.x) + bh(b.x) + bh(d.x) + bh(e.x);
            acc[2] += bl(a.y) + bl(b.y) + bl(d.y) + bl(e.y);
            acc[3] += bh(a.y) + bh(b.y) + bh(d.y) + bh(e.y);
            acc[4] += bl(a.z) + bl(b.z) + bl(d.z) + bl(e.z);
            acc[5] += bh(a.z) + bh(b.z) + bh(d.z) + bh(e.z);
            acc[6] += bl(a.w) + bl(b.w) + bl(d.w) + bl(e.w);
            acc[7] += bh(a.w) + bh(b.w) + bh(d.w) + bh(e.w);
        }
        float inv = 1.0f / fmaxf((float)dn, 1.0f);
        uint4 r = reinterpret_cast<const uint4*>(r1)[(size_t)n * 4 + c];
        float rr[8] = { bl(r.x), bh(r.x), bl(r.y), bh(r.y),
                        bl(r.z), bh(r.z), bl(r.w), bh(r.w) };
#pragma unroll
        for (int j = 0; j < 8; ++j)
            shh[(c * 8 + j) * 64 + loc] = fmaxf(acc[j] * inv + rr[j] + sb1[c * 8 + j], 0.f);
    }
    __syncthreads();

    if (valid) {
        float accp[4], accr[4];
#pragma unroll
        for (int j = 0; j < 4; ++j) { accp[j] = 0.f; accr[j] = 0.f; }
#pragma unroll
        for (int k = 0; k < 32; ++k) {
            float hk = shh[k * 64 + loc];
#pragma unroll
            for (int j = 0; j < 4; ++j) {
                accp[j] += hk * sW2l[k * 16 + c * 4 + j];
                accr[j] += hk * sW2r[k * 16 + c * 4 + j];
            }
        }
        uint2 up, ur;
        up.x = pack2(accp[0], accp[1]); up.y = pack2(accp[2], accp[3]);
        ur.x = pack2(accr[0], accr[1]); ur.y = pack2(accr[2], accr[3]);
        reinterpret_cast<uint2*>(P2)[(size_t)n * 4 + c] = up;
        reinterpret_cast<uint2*>(R2)[(size_t)n * 4 + c] = ur;
    } else if (n == NN) {                       // zero row for layer-2 pads
        uint2 z = make_uint2(0, 0);
        reinterpret_cast<uint2*>(P2)[(size_t)NN * 4 + c] = z;
        reinterpret_cast<uint2*>(R2)[(size_t)NN * 4 + c] = z;
    }
}

// ---- K4: layer2 gather (perm order, unroll-4) fused with final head ---------
__global__ __launch_bounds__(256) void gather2_kernel(
    const int* __restrict__ perm,
    const int* __restrict__ rowstart, const int* __restrict__ deg,
    const int* __restrict__ csr_src,
    const __hip_bfloat16* __restrict__ P2,
    const __hip_bfloat16* __restrict__ R2,
    const float* __restrict__ b2,       // [16]
    const float* __restrict__ Wlin,     // [16,2]
    const float* __restrict__ blin,     // [2]
    float* __restrict__ out)            // [NN,2]
{
    __shared__ float sb[16], sW[32], sbl[2];
    if (threadIdx.x < 16) sb[threadIdx.x] = b2[threadIdx.x];
    else if (threadIdx.x < 48) sW[threadIdx.x - 16] = Wlin[threadIdx.x - 16];
    else if (threadIdx.x < 50) sbl[threadIdx.x - 48] = blin[threadIdx.x - 48];
    __syncthreads();
    int t = blockIdx.x * 256 + threadIdx.x;
    int slot = t >> 1, c = t & 1;
    if (slot >= NSLOT) return;
    int n = perm[slot];
    if (n >= NN) return;
    int start = rowstart[n], dn = deg[n];
    int pv4 = ((dn + 3) & ~3) >> 2;

    float acc[8];
#pragma unroll
    for (int j = 0; j < 8; ++j) acc[j] = 0.f;
    const uint4* prow = reinterpret_cast<const uint4*>(P2);
    const int4* cp4 = reinterpret_cast<const int4*>(csr_src + start);
    for (int k = 0; k < pv4; ++k) {
        int4 s4 = cp4[k];
        uint4 a = prow[(size_t)s4.x * 2 + c];
        uint4 b = prow[(size_t)s4.y * 2 + c];
        uint4 d = prow[(size_t)s4.z * 2 + c];
        uint4 e = prow[(size_t)s4.w * 2 + c];
        acc[0] += bl(a.x) + bl(b.x) + bl(d.x) + bl(e.x);
        acc[1] += bh(a.x) + bh(b.x) + bh(d.x) + bh(e.x);
        acc[2] += bl(a.y) + bl(b.y) + bl(d.y) + bl(e.y);
        acc[3] += bh(a.y) + bh(b.y) + bh(d.y) + bh(e.y);
        acc[4] += bl(a.z) + bl(b.z) + bl(d.z) + bl(e.z);
        acc[5] += bh(a.z) + bh(b.z) + bh(d.z) + bh(e.z);
        acc[6] += bl(a.w) + bl(b.w) + bl(d.w) + bl(e.w);
        acc[7] += bh(a.w) + bh(b.w) + bh(d.w) + bh(e.w);
    }
    float inv = 1.0f / fmaxf((float)dn, 1.0f);
    uint4 r = reinterpret_cast<const uint4*>(R2)[(size_t)n * 2 + c];
    float rr[8] = { bl(r.x), bh(r.x), bl(r.y), bh(r.y),
                    bl(r.z), bh(r.z), bl(r.w), bh(r.w) };
    float o0 = 0.f, o1 = 0.f;
#pragma unroll
    for (int j = 0; j < 8; ++j) {
        int kk = c * 8 + j;
        float hv = fmaxf(acc[j] * inv + rr[j] + sb[kk], 0.f);
        o0 += hv * sW[kk * 2];
        o1 += hv * sW[kk * 2 + 1];
    }
    o0 += __shfl_xor(o0, 1, 64);
    o1 += __shfl_xor(o1, 1, 64);
    if (c == 0)
        reinterpret_cast<float2*>(out)[n] = make_float2(o0 + sbl[0], o1 + sbl[1]);
}

extern "C" void kernel_launch(void* const* d_in, const int* in_sizes, int n_in,
                              void* d_out, int out_size, void* d_ws, size_t ws_size,
                              hipStream_t stream)
{
    const float* x    = (const float*)d_in[0];
    const int*   ei   = (const int*)d_in[1];
    const float* W1l  = (const float*)d_in[2];
    const float* W1r  = (const float*)d_in[3];
    const float* b1   = (const float*)d_in[4];
    const float* W2l  = (const float*)d_in[5];
    const float* W2r  = (const float*)d_in[6];
    const float* b2   = (const float*)d_in[7];
    const float* Wlin = (const float*)d_in[8];
    const float* blin = (const float*)d_in[9];
    float* out = (float*)d_out;

    // ---- workspace layout (bytes; ws_size = 256 MiB) ----
    char* wsb = (char*)d_ws;
    int*      bsize    = (int*)(wsb + 64);               // int[NB]
    int*      deg      = (int*)(wsb + 4096);             // int[N]
    int*      rowstart = (int*)(wsb + 404096);           // int[N]
    int*      perm     = (int*)(wsb + 804096);           // int[NSLOT] 400 KB
    int*      csr_src  = (int*)(wsb + 1300000);          // int[NB*SEG] 8.41 MB
    unsigned* bbuf     = (unsigned*)(wsb + 9800000);     // u32[NB*CAP] 7.21 MB
    __hip_bfloat16* p1 = (__hip_bfloat16*)(wsb + 17100000); // bf16[N+1,32]
    __hip_bfloat16* r1 = (__hip_bfloat16*)(wsb + 23600000); // bf16[N,32]
    __hip_bfloat16* p2 = (__hip_bfloat16*)(wsb + 30100000); // bf16[N+1,16]
    __hip_bfloat16* r2 = (__hip_bfloat16*)(wsb + 33400000); // bf16[N+1,16]

    dim3 blk(256);

    hipMemsetAsync(bsize, 0, NB * sizeof(int), stream);
    k1_kernel<<<NCH + NB1, blk, 0, stream>>>(x, W1l, W1r, ei, bsize, bbuf, p1, r1);
    k2_kernel<<<NB, blk, 0, stream>>>(bsize, bbuf, deg, rowstart, csr_src, perm);
    gather1f_kernel<<<NSLOT / 64, blk, 0, stream>>>(
        perm, rowstart, deg, csr_src, p1, r1, b1, W2l, W2r, p2, r2);
    gather2_kernel<<<(NSLOT * 2 + 255) / 256, blk, 0, stream>>>(
        perm, rowstart, deg, csr_src, p2, r2, b2, Wlin, blin, out);
}

// Round 14
// 188.299 us; speedup vs baseline: 1.1000x; 1.1000x over previous
//
#include <hip/hip_runtime.h>
#include <hip/hip_bf16.h>

// FraudGNN: 2-layer GraphSAGE (mean aggr) + linear head.
// N=100000, E=1600000, feat 48 -> 32 -> 16 -> 2. fp32 in/out, int edge_index.
//
// R14 = R9 (the proven 187.7 us optimum) + rowstart/deg packed into int2
// (one 8B descriptor load per node in the gathers instead of two 4B loads).
// Post-mortem trail: R10 scalar-W (-31us), R11 bf16-packed-W (-13), R12
// unroll-8 (-4), R13 degree-sort perm (-19) ALL regressed vs R9 -> revert.
//
//  K1 = lin2 || bucket1 (block-ranged fusion, in-block int64 detect)
//  K2 = per-bucket CSR fill into fixed b*SEG region, x4-padded segments
//  K3 = gather1: 4 lanes/node, tail-free unroll-4, fused update + layer-2 proj
//  K4 = gather2: 2 lanes/node, unroll-4, fused final head
// Algebra: mean(x[src])@Wl == segsum((x@Wl)[src])/cnt -> project first,
// aggregate 32/16-wide bf16 rows by gather (zero float atomics).

constexpr int NN  = 100000;
constexpr int NE  = 1600000;
constexpr int NCH = (NN + 255) / 256;   // 391 node chunks (lin2 blocks)
constexpr int NB  = 391;                // buckets = dst >> 8
constexpr int CAP = 4608;               // per-bucket capacity (mean 4092, +8 sigma)
constexpr int SEG = CAP + 3 * 256;      // 5376: worst-case x4-padded footprint
constexpr int T1  = 2048;               // edges per bucket1 block
constexpr int EPT = T1 / 256;           // 8 edges cached per thread
constexpr int NB1 = (NE + T1 - 1) / T1; // 782 bucket1 blocks

__device__ __forceinline__ float bl(unsigned u) { return __uint_as_float(u << 16); }
__device__ __forceinline__ float bh(unsigned u) { return __uint_as_float(u & 0xffff0000u); }
__device__ __forceinline__ unsigned f2b(float x) {
    unsigned u = __float_as_uint(x);
    return (u + 0x7fffu + ((u >> 16) & 1u)) >> 16;
}
__device__ __forceinline__ unsigned pack2(float a, float b) {
    return f2b(a) | (f2b(b) << 16);
}

__device__ __forceinline__ int wave_incl_scan(int v, int lane) {
#pragma unroll
    for (int d = 1; d < 64; d <<= 1) {
        int t = __shfl_up(v, d, 64);
        if (lane >= d) v += t;
    }
    return v;
}

// ---- K1: lin2 (blocks [0,NCH)) || bucket1 (blocks [NCH, NCH+NB1)) ----------
__global__ __launch_bounds__(256) void k1_kernel(
    const float* __restrict__ X,
    const float* __restrict__ Wl,
    const float* __restrict__ Wr,
    const int*   __restrict__ ei,
    int* __restrict__ bsize, unsigned* __restrict__ bbuf,
    __hip_bfloat16* __restrict__ P, __hip_bfloat16* __restrict__ R)
{
    __shared__ float sW[2][48 * 32];            // 12 KB (lin part, fp32: proven optimum)
    __shared__ int hist[NB], base[NB], cur[NB]; // 4.7 KB (bucket part)
    __shared__ int s_any;

    if (blockIdx.x < NCH) {
        // ------ lin2: P = X@Wl, R = X@Wr (+ zero row at NN) ------
        for (int i = threadIdx.x; i < 48 * 32; i += 256) {
            sW[0][i] = Wl[i];
            sW[1][i] = Wr[i];
        }
        __syncthreads();
        int n = blockIdx.x * 256 + threadIdx.x;
        if (n > NN) return;
        if (n == NN) {                           // zero row (CSR pad target)
            uint4 z = make_uint4(0, 0, 0, 0);
            uint4* pp = reinterpret_cast<uint4*>(P + (size_t)NN * 32);
#pragma unroll
            for (int i = 0; i < 4; ++i) pp[i] = z;
            return;
        }
        float xr[48];
        const float4* xp = reinterpret_cast<const float4*>(X + (size_t)n * 48);
#pragma unroll
        for (int i = 0; i < 12; ++i) {
            float4 u = xp[i];
            xr[i*4+0] = u.x; xr[i*4+1] = u.y; xr[i*4+2] = u.z; xr[i*4+3] = u.w;
        }
        float accp[32], accr[32];
#pragma unroll
        for (int j = 0; j < 32; ++j) { accp[j] = 0.f; accr[j] = 0.f; }
#pragma unroll
        for (int k = 0; k < 48; ++k) {
            float xk = xr[k];
#pragma unroll
            for (int j = 0; j < 32; ++j) {
                accp[j] += xk * sW[0][k * 32 + j];
                accr[j] += xk * sW[1][k * 32 + j];
            }
        }
        uint4* pp = reinterpret_cast<uint4*>(P + (size_t)n * 32);
        uint4* rp = reinterpret_cast<uint4*>(R + (size_t)n * 32);
#pragma unroll
        for (int i = 0; i < 4; ++i) {
            uint4 u, v;
            u.x = pack2(accp[i*8+0], accp[i*8+1]); u.y = pack2(accp[i*8+2], accp[i*8+3]);
            u.z = pack2(accp[i*8+4], accp[i*8+5]); u.w = pack2(accp[i*8+6], accp[i*8+7]);
            v.x = pack2(accr[i*8+0], accr[i*8+1]); v.y = pack2(accr[i*8+2], accr[i*8+3]);
            v.z = pack2(accr[i*8+4], accr[i*8+5]); v.w = pack2(accr[i*8+6], accr[i*8+7]);
            pp[i] = u;
            rp[i] = v;
        }
    } else {
        // ------ bucket1: coarse sort edges by dst>>8 ------
        if (threadIdx.x == 0) s_any = 0;
        for (int i = threadIdx.x; i < NB; i += 256) { hist[i] = 0; cur[i] = 0; }
        __syncthreads();
        // self-detect edge_index layout: int64 -> odd words all zero
        int dv = 0;
        for (int i = threadIdx.x; i < 2048; i += 256) dv |= ei[2 * i + 1];
        if (dv != 0) atomicOr(&s_any, 1);
        __syncthreads();
        int sh = (s_any == 0) ? 1 : 0;

        int e0 = (blockIdx.x - NCH) * T1;
        int sreg[EPT], dreg[EPT];
#pragma unroll
        for (int it = 0; it < EPT; ++it) {
            int e = e0 + it * 256 + threadIdx.x;
            bool ok = e < NE;
            int s = ok ? ei[(size_t)e << sh] : -1;
            int d = ok ? ei[(size_t)(NE + e) << sh] : -1;
            if ((unsigned)s >= (unsigned)NN || (unsigned)d >= (unsigned)NN) { s = -1; d = -1; }
            sreg[it] = s; dreg[it] = d;
            if (d >= 0) atomicAdd(&hist[d >> 8], 1);
        }
        __syncthreads();
        for (int b = threadIdx.x; b < NB; b += 256) {
            int h = hist[b];
            base[b] = h ? atomicAdd(&bsize[b], h) : 0;
        }
        __syncthreads();
#pragma unroll
        for (int it = 0; it < EPT; ++it) {
            int s = sreg[it], d = dreg[it];
            if (d < 0) continue;
            int b = d >> 8;
            int pos = base[b] + atomicAdd(&cur[b], 1);
            if (pos < CAP)
                bbuf[(size_t)b * CAP + pos] = ((unsigned)s << 8) | (unsigned)(d & 255);
        }
    }
}

// ---- K2: per-bucket CSR fill into fixed region b*SEG, x4-padded segments ----
__global__ __launch_bounds__(256) void k2_kernel(
    const int* __restrict__ bsize, const unsigned* __restrict__ bbuf,
    int2* __restrict__ rowdeg, int* __restrict__ csr_src)
{
    __shared__ int ldeg[256], lcur[256], ws[4];
    int b = blockIdx.x, t = threadIdx.x;
    int bs = b * SEG;                       // fixed region: no cross-bucket coupling

    int S = min(bsize[b], CAP);
    const unsigned* bp = bbuf + (size_t)b * CAP;
    ldeg[t] = 0;
    __syncthreads();
    for (int i = t; i < S; i += 256)
        atomicAdd(&ldeg[bp[i] & 255u], 1);
    __syncthreads();

    int v  = ldeg[t];
    int pv = (v + 3) & ~3;                  // x4-padded per-node length
    int lane = t & 63, wid = t >> 6;
    int incl = wave_incl_scan(pv, lane);
    if (lane == 63) ws[wid] = incl;
    __syncthreads();
    int off = 0;
#pragma unroll
    for (int w = 0; w < 3; ++w)
        if (wid > w) off += ws[w];
    int excl = off + incl - pv;             // <= SEG - pv

    int node = (b << 8) + t;
    if (node < NN)
        rowdeg[node] = make_int2(bs + excl, v);   // {rowstart (4-aligned), deg}
    lcur[t] = excl;
    __syncthreads();

    for (int i = t; i < S; i += 256) {
        unsigned pk = bp[i];
        int pos = atomicAdd(&lcur[pk & 255u], 1);
        csr_src[bs + pos] = (int)(pk >> 8);
    }
    // pad tail of own node's segment with zero-row id (disjoint from fills)
    for (int p = excl + v; p < excl + pv; ++p)
        csr_src[bs + p] = NN;
}

// ---- K3: layer1 gather (unroll-4, int4 idx) + update + layer2 projections ---
__global__ __launch_bounds__(256) void gather1f_kernel(
    const int2* __restrict__ rowdeg,
    const int* __restrict__ csr_src,
    const __hip_bfloat16* __restrict__ p1,     // [N+1,32] (row NN = 0)
    const __hip_bfloat16* __restrict__ r1,     // [N,32]
    const float* __restrict__ b1,              // [32]
    const float* __restrict__ W2l,             // [32,16]
    const float* __restrict__ W2r,             // [32,16]
    __hip_bfloat16* __restrict__ P2,           // [N+1,16] (row NN = 0)
    __hip_bfloat16* __restrict__ R2)           // [N+1,16]
{
    __shared__ float sW2l[32 * 16], sW2r[32 * 16], sb1[32];
    __shared__ float shh[32 * 64];             // h exchange, 8 KB
    int t = threadIdx.x;
    for (int i = t; i < 32 * 16; i += 256) { sW2l[i] = W2l[i]; sW2r[i] = W2r[i]; }
    if (t < 32) sb1[t] = b1[t];
    __syncthreads();

    int loc = t >> 2, c = t & 3;
    int n = blockIdx.x * 64 + loc;
    bool valid = n < NN;

    if (valid) {
        int2 rd = rowdeg[n];
        int start = rd.x, dn = rd.y;
        int pv4 = ((dn + 3) & ~3) >> 2;
        float acc[8];
#pragma unroll
        for (int j = 0; j < 8; ++j) acc[j] = 0.f;
        const uint4* prow = reinterpret_cast<const uint4*>(p1);
        const int4* cp4 = reinterpret_cast<const int4*>(csr_src + start);
        for (int k = 0; k < pv4; ++k) {         // 4 row fetches in flight
            int4 s4 = cp4[k];
            uint4 a = prow[(size_t)s4.x * 4 + c];
            uint4 b = prow[(size_t)s4.y * 4 + c];
            uint4 d = prow[(size_t)s4.z * 4 + c];
            uint4 e = prow[(size_t)s4.w * 4 + c];
            acc[0] += bl(a.x) + bl(b.x) + bl(d.x) + bl(e.x);
            acc[1] += bh(a.x) + bh(b.x) + bh(d.x) + bh(e.x);
            acc[2] += bl(a.y) + bl(b.y) + bl(d.y) + bl(e.y);
            acc[3] += bh(a.y) + bh(b.y) + bh(d.y) + bh(e.y);
            acc[4] += bl(a.z) + bl(b.z) + bl(d.z) + bl(e.z);
            acc[5] += bh(a.z) + bh(b.z) + bh(d.z) + bh(e.z);
            acc[6] += bl(a.w) + bl(b.w) + bl(d.w) + bl(e.w);
            acc[7] += bh(a.w) + bh(b.w) + bh(d.w) + bh(e.w);
        }
        float inv = 1.0f / fmaxf((float)dn, 1.0f);
        uint4 r = reinterpret_cast<const uint4*>(r1)[(size_t)n * 4 + c];
        float rr[8] = { bl(r.x), bh(r.x), bl(r.y), bh(r.y),
                        bl(r.z), bh(r.z), bl(r.w), bh(r.w) };
#pragma unroll
        for (int j = 0; j < 8; ++j)
            shh[(c * 8 + j) * 64 + loc] = fmaxf(acc[j] * inv + rr[j] + sb1[c * 8 + j], 0.f);
    }
    __syncthreads();

    if (valid) {
        float accp[4], accr[4];
#pragma unroll
        for (int j = 0; j < 4; ++j) { accp[j] = 0.f; accr[j] = 0.f; }
#pragma unroll
        for (int k = 0; k < 32; ++k) {
            float hk = shh[k * 64 + loc];
#pragma unroll
            for (int j = 0; j < 4; ++j) {
                accp[j] += hk * sW2l[k * 16 + c * 4 + j];
                accr[j] += hk * sW2r[k * 16 + c * 4 + j];
            }
        }
        uint2 up, ur;
        up.x = pack2(accp[0], accp[1]); up.y = pack2(accp[2], accp[3]);
        ur.x = pack2(accr[0], accr[1]); ur.y = pack2(accr[2], accr[3]);
        reinterpret_cast<uint2*>(P2)[(size_t)n * 4 + c] = up;
        reinterpret_cast<uint2*>(R2)[(size_t)n * 4 + c] = ur;
    } else if (n == NN) {                       // zero row for layer-2 pads
        uint2 z = make_uint2(0, 0);
        reinterpret_cast<uint2*>(P2)[(size_t)NN * 4 + c] = z;
        reinterpret_cast<uint2*>(R2)[(size_t)NN * 4 + c] = z;
    }
}

// ---- K4: layer2 gather (unroll-4) fused with final head ---------------------
__global__ __launch_bounds__(256) void gather2_kernel(
    const int2* __restrict__ rowdeg,
    const int* __restrict__ csr_src,
    const __hip_bfloat16* __restrict__ P2,
    const __hip_bfloat16* __restrict__ R2,
    const float* __restrict__ b2,       // [16]
    const float* __restrict__ Wlin,     // [16,2]
    const float* __restrict__ blin,     // [2]
    float* __restrict__ out)            // [NN,2]
{
    __shared__ float sb[16], sW[32], sbl[2];
    if (threadIdx.x < 16) sb[threadIdx.x] = b2[threadIdx.x];
    else if (threadIdx.x < 48) sW[threadIdx.x - 16] = Wlin[threadIdx.x - 16];
    else if (threadIdx.x < 50) sbl[threadIdx.x - 48] = blin[threadIdx.x - 48];
    __syncthreads();
    int t = blockIdx.x * 256 + threadIdx.x;
    int n = t >> 1, c = t & 1;
    if (n >= NN) return;
    int2 rd = rowdeg[n];
    int start = rd.x, dn = rd.y;
    int pv4 = ((dn + 3) & ~3) >> 2;

    float acc[8];
#pragma unroll
    for (int j = 0; j < 8; ++j) acc[j] = 0.f;
    const uint4* prow = reinterpret_cast<const uint4*>(P2);
    const int4* cp4 = reinterpret_cast<const int4*>(csr_src + start);
    for (int k = 0; k < pv4; ++k) {
        int4 s4 = cp4[k];
        uint4 a = prow[(size_t)s4.x * 2 + c];
        uint4 b = prow[(size_t)s4.y * 2 + c];
        uint4 d = prow[(size_t)s4.z * 2 + c];
        uint4 e = prow[(size_t)s4.w * 2 + c];
        acc[0] += bl(a.x) + bl(b.x) + bl(d.x) + bl(e.x);
        acc[1] += bh(a.x) + bh(b.x) + bh(d.x) + bh(e.x);
        acc[2] += bl(a.y) + bl(b.y) + bl(d.y) + bl(e.y);
        acc[3] += bh(a.y) + bh(b.y) + bh(d.y) + bh(e.y);
        acc[4] += bl(a.z) + bl(b.z) + bl(d.z) + bl(e.z);
        acc[5] += bh(a.z) + bh(b.z) + bh(d.z) + bh(e.z);
        acc[6] += bl(a.w) + bl(b.w) + bl(d.w) + bl(e.w);
        acc[7] += bh(a.w) + bh(b.w) + bh(d.w) + bh(e.w);
    }
    float inv = 1.0f / fmaxf((float)dn, 1.0f);
    uint4 r = reinterpret_cast<const uint4*>(R2)[(size_t)n * 2 + c];
    float rr[8] = { bl(r.x), bh(r.x), bl(r.y), bh(r.y),
                    bl(r.z), bh(r.z), bl(r.w), bh(r.w) };
    float o0 = 0.f, o1 = 0.f;
#pragma unroll
    for (int j = 0; j < 8; ++j) {
        int kk = c * 8 + j;
        float hv = fmaxf(acc[j] * inv + rr[j] + sb[kk], 0.f);
        o0 += hv * sW[kk * 2];
        o1 += hv * sW[kk * 2 + 1];
    }
    o0 += __shfl_xor(o0, 1, 64);
    o1 += __shfl_xor(o1, 1, 64);
    if (c == 0)
        reinterpret_cast<float2*>(out)[n] = make_float2(o0 + sbl[0], o1 + sbl[1]);
}

extern "C" void kernel_launch(void* const* d_in, const int* in_sizes, int n_in,
                              void* d_out, int out_size, void* d_ws, size_t ws_size,
                              hipStream_t stream)
{
    const float* x    = (const float*)d_in[0];
    const int*   ei   = (const int*)d_in[1];
    const float* W1l  = (const float*)d_in[2];
    const float* W1r  = (const float*)d_in[3];
    const float* b1   = (const float*)d_in[4];
    const float* W2l  = (const float*)d_in[5];
    const float* W2r  = (const float*)d_in[6];
    const float* b2   = (const float*)d_in[7];
    const float* Wlin = (const float*)d_in[8];
    const float* blin = (const float*)d_in[9];
    float* out = (float*)d_out;

    // ---- workspace layout (bytes; ws_size = 256 MiB) ----
    char* wsb = (char*)d_ws;
    int*      bsize    = (int*)(wsb + 64);               // int[NB]
    int2*     rowdeg   = (int2*)(wsb + 4096);            // int2[N] {rowstart,deg}
    int*      csr_src  = (int*)(wsb + 804096);           // int[NB*SEG] 8.41 MB
    unsigned* bbuf     = (unsigned*)(wsb + 9300000);     // u32[NB*CAP] 7.21 MB
    __hip_bfloat16* p1 = (__hip_bfloat16*)(wsb + 16600000); // bf16[N+1,32]
    __hip_bfloat16* r1 = (__hip_bfloat16*)(wsb + 23100000); // bf16[N,32]
    __hip_bfloat16* p2 = (__hip_bfloat16*)(wsb + 29600000); // bf16[N+1,16]
    __hip_bfloat16* r2 = (__hip_bfloat16*)(wsb + 32900000); // bf16[N+1,16]

    dim3 blk(256);

    hipMemsetAsync(bsize, 0, NB * sizeof(int), stream);
    k1_kernel<<<NCH + NB1, blk, 0, stream>>>(x, W1l, W1r, ei, bsize, bbuf, p1, r1);
    k2_kernel<<<NB, blk, 0, stream>>>(bsize, bbuf, rowdeg, csr_src);
    gather1f_kernel<<<(NN + 1 + 63) / 64, blk, 0, stream>>>(
        rowdeg, csr_src, p1, r1, b1, W2l, W2r, p2, r2);
    gather2_kernel<<<(NN * 2 + 255) / 256, blk, 0, stream>>>(
        rowdeg, csr_src, p2, r2, b2, Wlin, blin, out);
}